// Round 9
// baseline (219.153 us; speedup 1.0000x reference)
//
#include <hip/hip_runtime.h>

// B=2, S=2048, D=1024, H=16, DH=64.
// 3 launches:
//  prep       : z<3: q/k/v fp32 -> bf16 (q->ws, k/v->d_out scratch);
//               z==3: W fp32 [k][n] -> bf16 Wt [n][k] (first 768 blocks).
//  proj_gemm  : z=3, Outh[w] = Xb @ Wt^T + bias. which==0 pre-scaled by
//               log2e/32 (exp2-domain); which==2 stored transposed [B][H][DH][S].
//  attn_kernel: flash attention, fixed-max exp2 softmax, 64 q/block ->
//               1024 blocks = 4/CU (LDS exactly 40960 B), mask via per-lane
//               global int4 + cndmask, swizzled P buffer, DMA dbuf K/V^T.

#define B_ 2
#define S_ 2048
#define D_ 1024
#define H_ 16
#define DH_ 64
#define M_ (B_*S_)   // 4096

#define WT_OFF  ((size_t)3*4194304)            // u16 offset of Wt
#define XB_OFF  (WT_OFF + (size_t)3*1048576)   // u16 offset of Xb slot (q)

typedef __attribute__((ext_vector_type(8))) short short8;
typedef __attribute__((ext_vector_type(4))) float f32x4;
#define MFMA16(a,b,c) __builtin_amdgcn_mfma_f32_16x16x32_bf16(a,b,c,0,0,0)

typedef __attribute__((address_space(1))) const void* gptr_t;
typedef __attribute__((address_space(3))) void* lptr_t;
static __device__ inline void gload_lds16(const void* g, void* l) {
    __builtin_amdgcn_global_load_lds((gptr_t)g, (lptr_t)l, 16, 0, 0);
}

static __device__ inline unsigned short f2bf(float x) {   // RNE
    union { float f; unsigned u; } v; v.f = x;
    return (unsigned short)((v.u + 0x7fffu + ((v.u >> 16) & 1u)) >> 16);
}
// pack two floats to bf16 pair (round-half-up): 2 adds + 1 v_perm_b32
static __device__ inline unsigned packp(float a, float b) {
    return __builtin_amdgcn_perm(__float_as_uint(b) + 0x8000u,
                                 __float_as_uint(a) + 0x8000u, 0x07060302u);
}

// ---------------------------------------------------------------------------
// prep: z<3 -> X convert (4096 blocks each); z==3 -> W transpose-convert
// (first 768 blocks: which = bx>>8, tile = bx&255).
// ---------------------------------------------------------------------------
__global__ __launch_bounds__(256) void prep(
    const float* __restrict__ X0, const float* __restrict__ X1,
    const float* __restrict__ X2,
    const float* __restrict__ Wq, const float* __restrict__ Wk,
    const float* __restrict__ Wv,
    unsigned short* __restrict__ O0, unsigned short* __restrict__ O1,
    unsigned short* __restrict__ O2, unsigned short* __restrict__ WtBase)
{
    const int z = blockIdx.z;
    const int t = threadIdx.x;
    if (z < 3) {
        const float* X = z==0 ? X0 : (z==1 ? X1 : X2);
        unsigned short* O = z==0 ? O0 : (z==1 ? O1 : O2);
        int idx = blockIdx.x*256 + t;
        float4 xv = *(const float4*)&X[(size_t)idx*4];
        uint2 o;
        o.x = (unsigned)f2bf(xv.x) | ((unsigned)f2bf(xv.y) << 16);
        o.y = (unsigned)f2bf(xv.z) | ((unsigned)f2bf(xv.w) << 16);
        *(uint2*)&O[(size_t)idx*4] = o;
        return;
    }
    // W transpose-convert
    const int bx = blockIdx.x;
    if (bx >= 768) return;
    const int which = bx >> 8;
    const int tile  = bx & 255;
    const float* W = which==0 ? Wq : (which==1 ? Wk : Wv);
    unsigned short* Out = WtBase + ((size_t)which << 20);

    __shared__ unsigned short T[64][72];
    const int n0 = (tile & 15)*64, k0 = (tile >> 4)*64;
    const int tk = t >> 4, tn4 = (t & 15)*4;

    #pragma unroll
    for (int i=0;i<4;i++){
        int kk = tk + i*16;
        float4 wv = *(const float4*)&W[(size_t)(k0+kk)*D_ + n0 + tn4];
        T[tn4+0][kk] = f2bf(wv.x);
        T[tn4+1][kk] = f2bf(wv.y);
        T[tn4+2][kk] = f2bf(wv.z);
        T[tn4+3][kk] = f2bf(wv.w);
    }
    __syncthreads();

    const int n = t >> 2, seg = t & 3;
    uint4 a = *(uint4*)&T[n][seg*16];
    uint4 b = *(uint4*)&T[n][seg*16 + 8];
    *(uint4*)&Out[(size_t)(n0+n)*D_ + k0 + seg*16]     = a;
    *(uint4*)&Out[(size_t)(n0+n)*D_ + k0 + seg*16 + 8] = b;
}

// ---------------------------------------------------------------------------
// Projection GEMM, pure-DMA staging, XOR-swizzled LDS. Grid (8,32,3).
// which==0: output scaled by log2e/32.  which==2: output transposed.
// ---------------------------------------------------------------------------
__global__ __launch_bounds__(256) void proj_gemm(
    const unsigned short* __restrict__ A0, const unsigned short* __restrict__ A1,
    const unsigned short* __restrict__ A2, const unsigned short* __restrict__ WtBase,
    const float* __restrict__ b0, const float* __restrict__ b1,
    const float* __restrict__ b2, unsigned short* __restrict__ OutBase)
{
    const int which = blockIdx.z;
    const unsigned short* A  = which==0 ? A0 : (which==1 ? A1 : A2);
    const unsigned short* Bm = WtBase + ((size_t)which << 20);
    const float* bias        = which==0 ? b0 : (which==1 ? b1 : b2);
    unsigned short* Out      = OutBase + ((size_t)which << 22);
    const float oscale = (which==0) ? 0.04508422f : 1.0f;   // log2e/32

    __shared__ __align__(16) unsigned short As[128*64];
    __shared__ __align__(16) unsigned short Bs[128*64];

    const int t    = threadIdx.x;
    const int m0   = blockIdx.y * 128;
    const int n0   = blockIdx.x * 128;
    const int w    = t >> 6;
    const int lane = t & 63;
    const int l15  = lane & 15;
    const int quad = lane >> 4;
    const int wm   = w >> 1, wn = w & 1;

    f32x4 acc[4][4];
    #pragma unroll
    for (int i=0;i<4;i++)
        #pragma unroll
        for (int j=0;j<4;j++) acc[i][j] = (f32x4){0.f,0.f,0.f,0.f};

    float biasv[4];
    #pragma unroll
    for (int nt=0; nt<4; nt++)
        biasv[nt] = bias[n0 + wn*64 + nt*16 + l15];

    int sArow[4], sAkc[4];
    #pragma unroll
    for (int i=0;i<4;i++){
        int s  = (w*4 + i)*64 + lane;
        int r  = s >> 3, cs = s & 7;
        sArow[i] = r;
        sAkc[i]  = ((cs ^ (r & 7)) * 8);
    }

    for (int ks = 0; ks < 16; ++ks) {
        const int kb = ks * 64;
        #pragma unroll
        for (int i=0;i<4;i++){
            int s = (w*4 + i)*64 + lane;
            gload_lds16(A  + (size_t)(m0 + sArow[i])*D_ + kb + sAkc[i], (unsigned short*)As + s*8);
            gload_lds16(Bm + (size_t)(n0 + sArow[i])*D_ + kb + sAkc[i], (unsigned short*)Bs + s*8);
        }
        __syncthreads();

        #pragma unroll
        for (int kh=0; kh<2; kh++){
            short8 aF[4], bF[4];
            #pragma unroll
            for (int mt=0; mt<4; mt++){
                int r  = wm*64 + mt*16 + l15;
                int cs = (kh*4 + quad) ^ (r & 7);
                aF[mt] = *(const short8*)(As + r*64 + cs*8);
            }
            #pragma unroll
            for (int nt=0; nt<4; nt++){
                int r  = wn*64 + nt*16 + l15;
                int cs = (kh*4 + quad) ^ (r & 7);
                bF[nt] = *(const short8*)(Bs + r*64 + cs*8);
            }
            #pragma unroll
            for (int mt=0; mt<4; mt++)
                #pragma unroll
                for (int nt=0; nt<4; nt++)
                    acc[mt][nt] = MFMA16(aF[mt], bF[nt], acc[mt][nt]);
        }
        __syncthreads();
    }

    if (which != 2) {
        #pragma unroll
        for (int nt=0; nt<4; nt++){
            int n  = n0 + wn*64 + nt*16 + l15;
            int hh = n >> 6, dh = n & 63;
            #pragma unroll
            for (int mt=0; mt<4; mt++){
                #pragma unroll
                for (int r=0; r<4; r++){
                    int m  = m0 + wm*64 + mt*16 + quad*4 + r;
                    int bb = m >> 11, ss = m & (S_-1);
                    float v = (acc[mt][nt][r] + biasv[nt]) * oscale;
                    Out[((size_t)((bb*H_ + hh)*S_ + ss))*DH_ + dh] = f2bf(v);
                }
            }
        }
    } else {
        #pragma unroll
        for (int nt=0; nt<4; nt++){
            int n  = n0 + wn*64 + nt*16 + l15;
            int hh = n >> 6, dh = n & 63;
            #pragma unroll
            for (int mt=0; mt<4; mt++){
                int m  = m0 + wm*64 + mt*16 + quad*4;
                int bb = m >> 11, ss = m & (S_-1);
                uint2 pk;
                pk.x = packp(acc[mt][nt][0] + biasv[nt], acc[mt][nt][1] + biasv[nt]);
                pk.y = packp(acc[mt][nt][2] + biasv[nt], acc[mt][nt][3] + biasv[nt]);
                *(uint2*)&Out[((size_t)((bb*H_ + hh)*DH_ + dh))*S_ + ss] = pk;
            }
        }
    }
}

// ---------------------------------------------------------------------------
// Flash attention, fixed-max exp2 softmax. Block = 64 q of one (b,h);
// 4 waves x 16 q. Grid 1024 blocks = 4/CU (LDS = 40960 B exactly).
// K/V^T DMA dbuf, 1 barrier/iter; mask via per-lane global int4 + cndmask;
// P buffer XOR-swizzled (no pad), wave-private round-trip.
// ---------------------------------------------------------------------------
__global__ __launch_bounds__(256,4) void attn_kernel(
    const unsigned short* __restrict__ ws, const int* __restrict__ mask,
    float* __restrict__ out)
{
    const unsigned short* Qh = ws;                      // [B][H][S][64], exp2-scaled
    const unsigned short* Kh = ws + (size_t)M_*D_;      // [B][H][S][64]
    const unsigned short* Vg = ws + 2*(size_t)M_*D_;    // [B][H][64][S]

    const int qt = blockIdx.x;   // 0..31
    const int h  = blockIdx.y;
    const int bb = blockIdx.z;
    const size_t base = ((size_t)(bb*H_ + h)) * S_ * DH_;
    const int q0 = qt * 64;

    __shared__ __align__(16) unsigned char smem[40960];
    unsigned short* KsB = (unsigned short*)smem;            // [2][64][64]
    unsigned short* VtB = (unsigned short*)(smem + 16384);  // [2][64][64]
    unsigned short* Pb  = (unsigned short*)(smem + 32768);  // [4][16][64] swz
    float*          Ob  = (float*)smem;                     // [64][68] alias

    const int t    = threadIdx.x;
    const int w    = t >> 6;
    const int lane = t & 63;
    const int l15  = lane & 15;
    const int quad = lane >> 4;
    const int sw   = l15 & 7;

    short8 qf0, qf1;
    {
        const unsigned short* qp = Qh + base + (size_t)(q0 + w*16 + l15)*DH_ + quad*8;
        qf0 = *(const short8*)(qp);
        qf1 = *(const short8*)(qp + 32);
    }

    f32x4 accO[4];
    #pragma unroll
    for (int i=0;i<4;i++) accO[i] = (f32x4){0.f,0.f,0.f,0.f};
    float l_run = 0.f;

    int rr[2], cc[2], ssl[2];
    #pragma unroll
    for (int i=0;i<2;i++){
        int s = (w*2 + i)*64 + lane;
        ssl[i] = s;
        rr[i]  = s >> 3;
        cc[i]  = ((s & 7) ^ (rr[i] & 7)) * 8;
    }

    #define ISSUE(k0v, p) do {                                                 \
        _Pragma("unroll")                                                      \
        for (int i=0;i<2;i++){                                                 \
            gload_lds16(Kh + base + (size_t)((k0v) + rr[i])*DH_ + cc[i],       \
                        KsB + (p)*4096 + ssl[i]*8);                            \
            gload_lds16(Vg + base + (size_t)rr[i]*S_ + (k0v) + cc[i],          \
                        VtB + (p)*4096 + ssl[i]*8);                            \
        }                                                                      \
    } while(0)

    ISSUE(0, 0);
    __syncthreads();

    for (int it = 0; it < 32; ++it){
        const int p = it & 1;
        if (it < 31) ISSUE((it+1)*64, 1-p);

        // per-lane mask words for this tile (L1-hot: 256 B shared block-wide)
        int4 mk[4];
        #pragma unroll
        for (int st=0; st<4; st++)
            mk[st] = *(const int4*)&mask[bb*S_ + it*64 + st*16 + quad*4];

        const unsigned short* Ks  = KsB + p*4096;
        const unsigned short* Vts = VtB + p*4096;

        // ---- scores: S^T = K·Q^T ----
        f32x4 sc[4];
        #pragma unroll
        for (int st=0; st<4; st++){
            int key = st*16 + l15;
            const unsigned short* kr = Ks + key*64;
            short8 ka = *(const short8*)(kr + ((quad    ) ^ (key & 7))*8);
            short8 kb = *(const short8*)(kr + ((quad + 4) ^ (key & 7))*8);
            f32x4 a = (f32x4){0.f,0.f,0.f,0.f};
            a = MFMA16(ka, qf0, a);
            a = MFMA16(kb, qf1, a);
            sc[st] = a;
        }

        // ---- fixed-max softmax: p = m ? exp2(s) : 0; lane-local l ----
        float lacc = 0.f;
        unsigned short* pr = Pb + (w*16 + l15)*64;
        #pragma unroll
        for (int st=0; st<4; st++){
            float pv[4];
            pv[0] = mk[st].x ? __builtin_amdgcn_exp2f(sc[st][0]) : 0.f;
            pv[1] = mk[st].y ? __builtin_amdgcn_exp2f(sc[st][1]) : 0.f;
            pv[2] = mk[st].z ? __builtin_amdgcn_exp2f(sc[st][2]) : 0.f;
            pv[3] = mk[st].w ? __builtin_amdgcn_exp2f(sc[st][3]) : 0.f;
            lacc += pv[0] + pv[1] + pv[2] + pv[3];
            uint2 pk;
            pk.x = packp(pv[0], pv[1]);
            pk.y = packp(pv[2], pv[3]);
            *(uint2*)(pr + (((st*2 + (quad>>1)) ^ sw)*8 + (quad&1)*4)) = pk;
        }
        l_run += lacc;

        // ---- PV: O^T += V^T · P^T (in-wave DS order covers P RAW) ----
        short8 pf0 = *(const short8*)(pr + ((quad    ) ^ sw)*8);
        short8 pf1 = *(const short8*)(pr + ((quad + 4) ^ sw)*8);
        #pragma unroll
        for (int mt=0; mt<4; mt++){
            int row = mt*16 + l15;
            const unsigned short* vr = Vts + row*64;
            short8 vf0 = *(const short8*)(vr + ((quad    ) ^ (row & 7))*8);
            short8 vf1 = *(const short8*)(vr + ((quad + 4) ^ (row & 7))*8);
            accO[mt] = MFMA16(vf0, pf0, accO[mt]);
            accO[mt] = MFMA16(vf1, pf1, accO[mt]);
        }

        __syncthreads();   // drains DMA (it+1 ready), protects buffers
    }

    // ---- epilogue: reduce l across quads once, normalize, transpose, store ----
    float l = l_run;
    l += __shfl_xor(l, 16);
    l += __shfl_xor(l, 32);
    float invl = 1.0f / fmaxf(l, 1e-30f);
    #pragma unroll
    for (int mt=0; mt<4; mt++)
        #pragma unroll
        for (int r=0; r<4; r++)
            Ob[(w*16 + l15)*68 + mt*16 + quad*4 + r] = accO[mt][r]*invl;
    __syncthreads();

    #pragma unroll
    for (int i=0;i<4;i++){
        int f  = (i*256 + t)*4;     // 4096 floats
        int qq = f >> 6, dh = f & 63;
        float4 o = *(float4*)&Ob[qq*68 + dh];
        *(float4*)&out[((size_t)(bb*S_ + q0 + qq))*D_ + h*DH_ + dh] = o;
    }
    #undef ISSUE
}

extern "C" void kernel_launch(void* const* d_in, const int* in_sizes, int n_in,
                              void* d_out, int out_size, void* d_ws, size_t ws_size,
                              hipStream_t stream) {
    const float* q    = (const float*)d_in[0];
    const float* k    = (const float*)d_in[1];
    const float* v    = (const float*)d_in[2];
    const int*   mask = (const int*)d_in[3];
    const float* Wq   = (const float*)d_in[4];
    const float* b0   = (const float*)d_in[5];
    const float* Wk   = (const float*)d_in[6];
    const float* b1   = (const float*)d_in[7];
    const float* Wv   = (const float*)d_in[8];
    const float* b2   = (const float*)d_in[9];
    float* out = (float*)d_out;
    unsigned short* ws = (unsigned short*)d_ws;   // 39.85 MB used

    // Xb slots: q -> ws; k,v -> d_out (scratch until attn overwrites it last)
    unsigned short* xq = ws + XB_OFF;
    unsigned short* xk = (unsigned short*)d_out;
    unsigned short* xv = (unsigned short*)d_out + 4194304;

    prep<<<dim3(4096,1,4), 256, 0, stream>>>(q, k, v, Wq, Wk, Wv,
                                             xq, xk, xv, ws + WT_OFF);
    proj_gemm<<<dim3(8,32,3), 256, 0, stream>>>(xq, xk, xv, ws + WT_OFF,
                                                b0, b1, b2, ws);
    attn_kernel<<<dim3(32,16,2), 256, 0, stream>>>(ws, mask, out);
}